// Round 1
// baseline (2362.712 us; speedup 1.0000x reference)
//
#include <hip/hip_runtime.h>

// Laplacian-kernel regression, fused (no kmat materialization).
// Round 1: correctness-first fp32 VALU version.
//   out[N,Y] = exp(-sqrt(sum_d (x-z)^2)/10) @ W
// Grid: (N/BM row tiles) x (MCHUNKS M-chunks); partial outputs combined via
// fp32 atomicAdd after hipMemsetAsync(d_out, 0).

constexpr int N_ = 8192, M_ = 8192, D_ = 512, Y_ = 256;
constexpr int BM = 64, BN = 64, BK = 64;
constexpr int MCHUNKS = 4;
constexpr int MCHUNK  = M_ / MCHUNKS;   // 2048
constexpr int MSTEPS  = MCHUNK / BN;    // 32
constexpr int DSTEPS  = D_ / BK;        // 8
constexpr int LDA  = BK + 1;            // 65: 4*65 mod 32 = 4 -> sZ reads spread 8 banks (2-way, free)
constexpr int LDSS = BN + 1;            // 65

__global__ __launch_bounds__(256, 3) void laplace_fused_v1(
    const float* __restrict__ X, const float* __restrict__ Z,
    const float* __restrict__ W, float* __restrict__ O)
{
    __shared__ float sX[BM * LDA];   // 16.6 KB
    __shared__ float sZ[BN * LDA];   // 16.6 KB
    __shared__ float sS[BM * LDSS];  // 16.6 KB  -> ~50 KB total, 3 blocks/CU

    const int t   = threadIdx.x;     // 256 threads
    const int pr  = t >> 4;          // 0..15: row group (rows pr*4..pr*4+3)
    const int pc  = t & 15;          // 0..15: col group (cols pc*4..pc*4+3)
    const int sc4 = pc * 4;
    const int row0  = blockIdx.x * BM;
    const int mbase = blockIdx.y * MCHUNK;

    // output accumulators: o[i][yb][j] -> out[row0+pr*4+i][yb*64 + pc*4 + j]
    float o[4][4][4];
    #pragma unroll
    for (int i = 0; i < 4; ++i)
        #pragma unroll
        for (int yb = 0; yb < 4; ++yb)
            #pragma unroll
            for (int j = 0; j < 4; ++j) o[i][yb][j] = 0.0f;

    for (int ms = 0; ms < MSTEPS; ++ms) {
        const int zrow0 = mbase + ms * BN;

        float s[4][4];
        #pragma unroll
        for (int i = 0; i < 4; ++i)
            #pragma unroll
            for (int j = 0; j < 4; ++j) s[i][j] = 0.0f;

        for (int kk = 0; kk < DSTEPS; ++kk) {
            const int k0 = kk * BK;
            __syncthreads();  // previous tile consumers done before restage
            // stage X[64x64] and Z[64x64]: thread loads one float4 per 16-row rep
            #pragma unroll
            for (int rep = 0; rep < 4; ++rep) {
                const int r = pr + rep * 16;
                const float4 xv = *reinterpret_cast<const float4*>(
                    X + (size_t)(row0 + r) * D_ + k0 + sc4);
                const float4 zv = *reinterpret_cast<const float4*>(
                    Z + (size_t)(zrow0 + r) * D_ + k0 + sc4);
                float* dx = sX + r * LDA + sc4;   // LDA odd: scalar stores (16B-align unsafe)
                dx[0] = xv.x; dx[1] = xv.y; dx[2] = xv.z; dx[3] = xv.w;
                float* dz = sZ + r * LDA + sc4;
                dz[0] = zv.x; dz[1] = zv.y; dz[2] = zv.z; dz[3] = zv.w;
            }
            __syncthreads();
            // d2 accumulation: s[i][j] += (x - z)^2 over this k-slab
            #pragma unroll 4
            for (int k = 0; k < BK; ++k) {
                float xr[4], zc[4];
                #pragma unroll
                for (int i = 0; i < 4; ++i) xr[i] = sX[(pr * 4 + i) * LDA + k];
                #pragma unroll
                for (int j = 0; j < 4; ++j) zc[j] = sZ[(pc * 4 + j) * LDA + k];
                #pragma unroll
                for (int i = 0; i < 4; ++i)
                    #pragma unroll
                    for (int j = 0; j < 4; ++j) {
                        const float d = xr[i] - zc[j];
                        s[i][j] = fmaf(d, d, s[i][j]);
                    }
            }
        }

        // kmat tile = exp(-sqrt(d2)/10) -> LDS (previous PV readers finished:
        // D-loop barriers above dominate)
        #pragma unroll
        for (int i = 0; i < 4; ++i)
            #pragma unroll
            for (int j = 0; j < 4; ++j)
                sS[(pr * 4 + i) * LDSS + sc4 + j] = __expf(-sqrtf(s[i][j]) * 0.1f);
        __syncthreads();

        // PV: o += kmat_tile[64x64] @ W[zrow0..zrow0+63][0..255]
        #pragma unroll 2
        for (int c = 0; c < BN; ++c) {
            float sv[4];
            #pragma unroll
            for (int i = 0; i < 4; ++i) sv[i] = sS[(pr * 4 + i) * LDSS + c];
            const float* wrow = W + (size_t)(zrow0 + c) * Y_;
            #pragma unroll
            for (int yb = 0; yb < 4; ++yb) {
                const float4 wv = *reinterpret_cast<const float4*>(wrow + yb * 64 + sc4);
                #pragma unroll
                for (int i = 0; i < 4; ++i) {
                    o[i][yb][0] = fmaf(sv[i], wv.x, o[i][yb][0]);
                    o[i][yb][1] = fmaf(sv[i], wv.y, o[i][yb][1]);
                    o[i][yb][2] = fmaf(sv[i], wv.z, o[i][yb][2]);
                    o[i][yb][3] = fmaf(sv[i], wv.w, o[i][yb][3]);
                }
            }
        }
    }

    // accumulate partial output (4 M-chunks race per element -> atomic)
    #pragma unroll
    for (int i = 0; i < 4; ++i) {
        const size_t rbase = (size_t)(row0 + pr * 4 + i) * Y_;
        #pragma unroll
        for (int yb = 0; yb < 4; ++yb)
            #pragma unroll
            for (int j = 0; j < 4; ++j)
                atomicAdd(O + rbase + yb * 64 + sc4 + j, o[i][yb][j]);
    }
}

extern "C" void kernel_launch(void* const* d_in, const int* in_sizes, int n_in,
                              void* d_out, int out_size, void* d_ws, size_t ws_size,
                              hipStream_t stream) {
    const float* X = (const float*)d_in[0];   // batch   [8192, 512]
    const float* Z = (const float*)d_in[1];   // centers [8192, 512]
    const float* W = (const float*)d_in[2];   // weight  [8192, 256]
    float* O = (float*)d_out;                 // pred    [8192, 256]

    hipMemsetAsync(d_out, 0, (size_t)out_size * sizeof(float), stream);
    dim3 grid(N_ / BM, MCHUNKS);
    laplace_fused_v1<<<grid, dim3(256), 0, stream>>>(X, Z, W, O);
}

// Round 3
// 341.938 us; speedup vs baseline: 6.9098x; 6.9098x over previous
//
#include <hip/hip_runtime.h>

// Laplacian-kernel regression, fused flash-style, bf16 MFMA (32x32x16).
//   d2 = ||x||^2 + ||z||^2 - 2 X.Z^T ; P = exp(-sqrt(d2)/10) ; out = P @ W
// Prep: cast X,Z -> bf16 + row norms; W -> bf16 transposed Wt[256][8192] (in d_ws).
// Main: 512 thr (8 waves), BM=128 rows x all Y=256, loop M in BN=128 tiles.
//       QK MFMA -> transform in C-layout regs -> P to LDS (A-layout) -> PV MFMA.
// Grid 64 row-tiles x 4 M-chunks; fp32 atomicAdd combine after memset.
// R2 fix: PV sW staging was 2 reps (half the 256x64 tile) -> 4 reps.

using frag8  = __attribute__((ext_vector_type(8))) short;   // 8 bf16 (4 VGPRs)
using f32x16 = __attribute__((ext_vector_type(16))) float;  // 32x32 C/D frag

constexpr int Nn = 8192, Mm = 8192, Dd = 512, Yd = 256;
constexpr int BM = 128, BN = 128, BK = 64;
constexpr int MCH = 4, MPER = Mm / MCH, MT = MPER / BN;     // 4 chunks, 16 tiles each
constexpr int LDX = BK + 8;    // 72 bf16: 144B rows, 16B-aligned for ds_read_b128
constexpr int LDP = BN + 8;    // 136
constexpr int LDW = 64 + 8;    // 72

// workspace layout (bytes)
constexpr size_t OFF_XB  = 0;
constexpr size_t OFF_ZB  = OFF_XB + (size_t)Nn * Dd * 2;    //  8 MB
constexpr size_t OFF_WT  = OFF_ZB + (size_t)Mm * Dd * 2;    // 16 MB
constexpr size_t OFF_XSQ = OFF_WT + (size_t)Yd * Mm * 2;    // 20 MB
constexpr size_t OFF_ZSQ = OFF_XSQ + (size_t)Nn * 4;
constexpr size_t WS_NEED = OFF_ZSQ + (size_t)Mm * 4;        // ~21 MB

__device__ __forceinline__ ushort f2bf(float f) {
    unsigned u = __builtin_bit_cast(unsigned, f);
    u += 0x7FFFu + ((u >> 16) & 1u);          // RNE; inputs are finite/normal
    return (ushort)(u >> 16);
}

// ---- prep 1: bf16 cast + row squared-norms (one wave per row of 512) ----
__global__ __launch_bounds__(256) void cast_norm(const float* __restrict__ src,
                                                 ushort* __restrict__ dst,
                                                 float* __restrict__ nrm) {
    const int wid = threadIdx.x >> 6, lane = threadIdx.x & 63;
    const int row = blockIdx.x * 4 + wid;
    const float* s = src + (size_t)row * Dd + lane * 8;
    const float4 a = ((const float4*)s)[0];
    const float4 b = ((const float4*)s)[1];
    uint4 pk;
    pk.x = (unsigned)f2bf(a.x) | ((unsigned)f2bf(a.y) << 16);
    pk.y = (unsigned)f2bf(a.z) | ((unsigned)f2bf(a.w) << 16);
    pk.z = (unsigned)f2bf(b.x) | ((unsigned)f2bf(b.y) << 16);
    pk.w = (unsigned)f2bf(b.z) | ((unsigned)f2bf(b.w) << 16);
    *(uint4*)(dst + (size_t)row * Dd + lane * 8) = pk;
    float sq = a.x*a.x + a.y*a.y + a.z*a.z + a.w*a.w
             + b.x*b.x + b.y*b.y + b.z*b.z + b.w*b.w;
    #pragma unroll
    for (int off = 32; off; off >>= 1) sq += __shfl_xor(sq, off);
    if (lane == 0) nrm[row] = sq;
}

// ---- prep 2: W[8192][256] fp32 -> Wt[256][8192] bf16 (LDS-tiled transpose) ----
__global__ __launch_bounds__(256) void transpose_w(const float* __restrict__ Wf,
                                                   ushort* __restrict__ Wt) {
    __shared__ float tile[64][65];
    const int m0 = blockIdx.x * 64, n0 = blockIdx.y * 64;
    const int t = threadIdx.x;
    #pragma unroll
    for (int rep = 0; rep < 4; ++rep) {
        const int r = rep * 16 + (t >> 4), c4 = (t & 15) * 4;
        const float4 v = *(const float4*)(Wf + (size_t)(m0 + r) * Yd + n0 + c4);
        tile[r][c4] = v.x; tile[r][c4+1] = v.y; tile[r][c4+2] = v.z; tile[r][c4+3] = v.w;
    }
    __syncthreads();
    #pragma unroll
    for (int rep = 0; rep < 4; ++rep) {
        const int n = rep * 16 + (t >> 4), m4 = (t & 15) * 4;
        ushort4 pk;
        pk.x = f2bf(tile[m4+0][n]); pk.y = f2bf(tile[m4+1][n]);
        pk.z = f2bf(tile[m4+2][n]); pk.w = f2bf(tile[m4+3][n]);
        *(ushort4*)(Wt + (size_t)(n0 + n) * Mm + m0 + m4) = pk;
    }
}

// ---- main fused kernel ----
__global__ __launch_bounds__(512, 2) void laplace_mfma(
    const ushort* __restrict__ Xb, const ushort* __restrict__ Zb,
    const ushort* __restrict__ Wt, const float* __restrict__ xsqg,
    const float* __restrict__ zsqg, float* __restrict__ O)
{
    // smem: [0,36864) = sX(18432)+sZ(18432), aliased by sW(36864) in PV phase;
    //       [36864, 71680) = sP; [71680, 72704) = norms.
    __shared__ __align__(16) char smem[72704];
    ushort* sX = (ushort*)smem;
    ushort* sZ = sX + BM * LDX;
    ushort* sW = (ushort*)smem;                 // alias (phase-disjoint)
    ushort* sP = (ushort*)(smem + 36864);
    float* sXsq = (float*)(smem + 71680);
    float* sZsq = sXsq + 128;

    const int t = threadIdx.x;
    const int wid = t >> 6, lane = t & 63;
    const int lm = lane & 31, lh = lane >> 5;
    const int rq = wid >> 1;                    // QK/PV row-frag (32 rows)
    const int cpair = (wid & 1) * 2;            // QK col-frag pair (of 4)
    const int cbase = (wid & 1) * 4;            // PV col-frags cbase..cbase+3 (of 8)
    const int row0 = blockIdx.x * BM;
    const int zbase = blockIdx.y * MPER;

    if (t < 128) sXsq[t] = xsqg[row0 + t];

    f32x16 Oa[4];
    #pragma unroll
    for (int j = 0; j < 4; ++j)
        #pragma unroll
        for (int r = 0; r < 16; ++r) Oa[j][r] = 0.0f;

    for (int mt = 0; mt < MT; ++mt) {
        const int zrow0 = zbase + mt * BN;
        if (t < 128) sZsq[t] = zsqg[zrow0 + t];   // made visible by kk=0 barrier

        f32x16 S0, S1;
        #pragma unroll
        for (int r = 0; r < 16; ++r) { S0[r] = 0.0f; S1[r] = 0.0f; }

        // ---- QK: S = X_tile . Z_tile^T, K=512 in 8 slabs of 64 ----
        for (int kk = 0; kk < Dd / BK; ++kk) {
            __syncthreads();   // prev slab MFMA reads / prev tile sW reads done
            const ushort* xsrc = Xb + (size_t)row0 * Dd + kk * BK;
            const ushort* zsrc = Zb + (size_t)zrow0 * Dd + kk * BK;
            #pragma unroll
            for (int rep = 0; rep < 2; ++rep) {
                const int idx = rep * 512 + t;
                const int r = idx >> 3, c = idx & 7;
                *(uint4*)(sX + r * LDX + c * 8) =
                    *(const uint4*)(xsrc + (size_t)r * Dd + c * 8);
                *(uint4*)(sZ + r * LDX + c * 8) =
                    *(const uint4*)(zsrc + (size_t)r * Dd + c * 8);
            }
            __syncthreads();
            const ushort* ax  = sX + (rq * 32 + lm) * LDX + lh * 8;
            const ushort* bz0 = sZ + (cpair * 32 + lm) * LDX + lh * 8;
            const ushort* bz1 = bz0 + 32 * LDX;
            #pragma unroll
            for (int ks = 0; ks < 4; ++ks) {
                const frag8 a  = *(const frag8*)(ax + ks * 16);
                const frag8 b0 = *(const frag8*)(bz0 + ks * 16);
                const frag8 b1 = *(const frag8*)(bz1 + ks * 16);
                S0 = __builtin_amdgcn_mfma_f32_32x32x16_bf16(a, b0, S0, 0, 0, 0);
                S1 = __builtin_amdgcn_mfma_f32_32x32x16_bf16(a, b1, S1, 0, 0, 0);
            }
        }

        // ---- transform: d2 -> exp(-dist/10), write P (bf16) to LDS A-layout ----
        #pragma unroll
        for (int reg = 0; reg < 16; ++reg) {
            const int row = rq * 32 + (reg & 3) + 8 * (reg >> 2) + 4 * lh;
            const float xs = sXsq[row];
            {
                const int col = cpair * 32 + lm;
                const float d2 = fmaxf(xs + sZsq[col] - 2.0f * S0[reg], 0.0f);
                sP[row * LDP + col] = f2bf(__expf(-0.1f * __builtin_sqrtf(d2)));
            }
            {
                const int col = (cpair + 1) * 32 + lm;
                const float d2 = fmaxf(xs + sZsq[col] - 2.0f * S1[reg], 0.0f);
                sP[row * LDP + col] = f2bf(__expf(-0.1f * __builtin_sqrtf(d2)));
            }
        }
        __syncthreads();   // sP visible; sX/sZ reads done -> sW may overwrite

        // ---- PV: O += P[128x128] . W[128x256], in two K-halves of 64 ----
        const ushort* ap = sP + (rq * 32 + lm) * LDP + lh * 8;
        #pragma unroll
        for (int half = 0; half < 2; ++half) {
            // stage sW[256][64]: 256 rows x 64 bf16 = 2048 uint4, 512 thr x 4 reps
            #pragma unroll
            for (int rep = 0; rep < 4; ++rep) {
                const int idx = rep * 512 + t;
                const int n = idx >> 3, c = idx & 7;
                *(uint4*)(sW + n * LDW + c * 8) =
                    *(const uint4*)(Wt + (size_t)n * Mm + zrow0 + half * 64 + c * 8);
            }
            __syncthreads();
            #pragma unroll
            for (int ks = 0; ks < 4; ++ks) {
                const frag8 a = *(const frag8*)(ap + half * 64 + ks * 16);
                #pragma unroll
                for (int j = 0; j < 4; ++j) {
                    const frag8 b = *(const frag8*)(
                        sW + ((cbase + j) * 32 + lm) * LDW + ks * 16 + lh * 8);
                    Oa[j] = __builtin_amdgcn_mfma_f32_32x32x16_bf16(a, b, Oa[j], 0, 0, 0);
                }
            }
            if (half == 0) __syncthreads();   // sW reads done before restage
        }
    }

    // ---- epilogue: combine 4 M-chunks via fp32 atomics ----
    #pragma unroll
    for (int j = 0; j < 4; ++j) {
        const int col = (cbase + j) * 32 + lm;
        #pragma unroll
        for (int reg = 0; reg < 16; ++reg) {
            const int row = row0 + rq * 32 + (reg & 3) + 8 * (reg >> 2) + 4 * lh;
            atomicAdd(&O[(size_t)row * Yd + col], Oa[j][reg]);
        }
    }
}

// ---- fallback (round-1 fp32 kernel) if workspace is too small ----
constexpr int FBM = 64, FBN = 64, FBK = 64;
constexpr int FMCH = 4, FMCHUNK = Mm / FMCH, FMSTEPS = FMCHUNK / FBN, FDSTEPS = Dd / FBK;
constexpr int FLDA = FBK + 1, FLDSS = FBN + 1;

__global__ __launch_bounds__(256, 3) void laplace_fused_v1(
    const float* __restrict__ X, const float* __restrict__ Z,
    const float* __restrict__ W, float* __restrict__ O)
{
    __shared__ float sX[FBM * FLDA];
    __shared__ float sZ[FBN * FLDA];
    __shared__ float sS[FBM * FLDSS];
    const int t = threadIdx.x, pr = t >> 4, pc = t & 15, sc4 = pc * 4;
    const int row0 = blockIdx.x * FBM, mbase = blockIdx.y * FMCHUNK;
    float o[4][4][4];
    #pragma unroll
    for (int i = 0; i < 4; ++i)
        for (int yb = 0; yb < 4; ++yb)
            for (int j = 0; j < 4; ++j) o[i][yb][j] = 0.0f;
    for (int ms = 0; ms < FMSTEPS; ++ms) {
        const int zrow0 = mbase + ms * FBN;
        float s[4][4];
        #pragma unroll
        for (int i = 0; i < 4; ++i)
            for (int j = 0; j < 4; ++j) s[i][j] = 0.0f;
        for (int kk = 0; kk < FDSTEPS; ++kk) {
            const int k0 = kk * FBK;
            __syncthreads();
            #pragma unroll
            for (int rep = 0; rep < 4; ++rep) {
                const int r = pr + rep * 16;
                const float4 xv = *reinterpret_cast<const float4*>(X + (size_t)(row0 + r) * Dd + k0 + sc4);
                const float4 zv = *reinterpret_cast<const float4*>(Z + (size_t)(zrow0 + r) * Dd + k0 + sc4);
                float* dx = sX + r * FLDA + sc4;
                dx[0] = xv.x; dx[1] = xv.y; dx[2] = xv.z; dx[3] = xv.w;
                float* dz = sZ + r * FLDA + sc4;
                dz[0] = zv.x; dz[1] = zv.y; dz[2] = zv.z; dz[3] = zv.w;
            }
            __syncthreads();
            #pragma unroll 4
            for (int k = 0; k < FBK; ++k) {
                float xr[4], zc[4];
                #pragma unroll
                for (int i = 0; i < 4; ++i) xr[i] = sX[(pr * 4 + i) * FLDA + k];
                #pragma unroll
                for (int j = 0; j < 4; ++j) zc[j] = sZ[(pc * 4 + j) * FLDA + k];
                #pragma unroll
                for (int i = 0; i < 4; ++i)
                    #pragma unroll
                    for (int j = 0; j < 4; ++j) {
                        const float d = xr[i] - zc[j];
                        s[i][j] = fmaf(d, d, s[i][j]);
                    }
            }
        }
        #pragma unroll
        for (int i = 0; i < 4; ++i)
            for (int j = 0; j < 4; ++j)
                sS[(pr * 4 + i) * FLDSS + sc4 + j] = __expf(-sqrtf(s[i][j]) * 0.1f);
        __syncthreads();
        #pragma unroll 2
        for (int c = 0; c < FBN; ++c) {
            float sv[4];
            #pragma unroll
            for (int i = 0; i < 4; ++i) sv[i] = sS[(pr * 4 + i) * FLDSS + c];
            const float* wrow = W + (size_t)(zrow0 + c) * Yd;
            #pragma unroll
            for (int yb = 0; yb < 4; ++yb) {
                const float4 wv = *reinterpret_cast<const float4*>(wrow + yb * 64 + sc4);
                #pragma unroll
                for (int i = 0; i < 4; ++i) {
                    o[i][yb][0] = fmaf(sv[i], wv.x, o[i][yb][0]);
                    o[i][yb][1] = fmaf(sv[i], wv.y, o[i][yb][1]);
                    o[i][yb][2] = fmaf(sv[i], wv.z, o[i][yb][2]);
                    o[i][yb][3] = fmaf(sv[i], wv.w, o[i][yb][3]);
                }
            }
        }
        __syncthreads();
    }
    #pragma unroll
    for (int i = 0; i < 4; ++i) {
        const size_t rbase = (size_t)(row0 + pr * 4 + i) * Yd;
        #pragma unroll
        for (int yb = 0; yb < 4; ++yb)
            for (int j = 0; j < 4; ++j)
                atomicAdd(O + rbase + yb * 64 + sc4 + j, o[i][yb][j]);
    }
}

extern "C" void kernel_launch(void* const* d_in, const int* in_sizes, int n_in,
                              void* d_out, int out_size, void* d_ws, size_t ws_size,
                              hipStream_t stream) {
    const float* X = (const float*)d_in[0];   // batch   [8192, 512]
    const float* Z = (const float*)d_in[1];   // centers [8192, 512]
    const float* W = (const float*)d_in[2];   // weight  [8192, 256]
    float* O = (float*)d_out;                 // pred    [8192, 256]

    hipMemsetAsync(d_out, 0, (size_t)out_size * sizeof(float), stream);

    if (ws_size < WS_NEED) {   // ws_size is call-invariant -> deterministic path
        dim3 grid(Nn / FBM, FMCH);
        laplace_fused_v1<<<grid, dim3(256), 0, stream>>>(X, Z, W, O);
        return;
    }

    char* ws = (char*)d_ws;
    ushort* Xb  = (ushort*)(ws + OFF_XB);
    ushort* Zb  = (ushort*)(ws + OFF_ZB);
    ushort* Wt  = (ushort*)(ws + OFF_WT);
    float*  xsq = (float*)(ws + OFF_XSQ);
    float*  zsq = (float*)(ws + OFF_ZSQ);

    cast_norm<<<dim3(Nn / 4), dim3(256), 0, stream>>>(X, Xb, xsq);
    cast_norm<<<dim3(Mm / 4), dim3(256), 0, stream>>>(Z, Zb, zsq);
    transpose_w<<<dim3(Mm / 64, Yd / 64), dim3(256), 0, stream>>>(W, Wt);

    dim3 grid(Nn / BM, MCH);
    laplace_mfma<<<grid, dim3(512), 0, stream>>>(Xb, Zb, Wt, xsq, zsq, O);
}